// Round 13
// baseline (130.447 us; speedup 1.0000x reference)
//
#include <hip/hip_runtime.h>
#include <hip/hip_bf16.h>
#include <stdint.h>

// Problem constants
#define NB 8
#define NP 225      // patches per image
#define PGRID 15    // 15x15 patch grid
#define DH 256      // hidden
#define DIN 130     // per-node feature dim

typedef _Float16 f16x8 __attribute__((ext_vector_type(8)));   // 8 f16 = 4 VGPRs
typedef float    f32x4 __attribute__((ext_vector_type(4)));

static __device__ __forceinline__ float lrelu(float x) { return fmaxf(x, 0.01f * x); }

// ---------------------------------------------------------------------------
// K1 (fused prep): blocks 0..359 = pool+patch+U/V projection (f32 math, f16
// store) + accg zeroing; blocks 360..391 = W1 repack to fragment-linear f16.
__global__ void prep_kernel(const float* __restrict__ x, const float* __restrict__ W0,
                            const float* __restrict__ b0, const float* __restrict__ W1,
                            _Float16* __restrict__ U, _Float16* __restrict__ V,
                            _Float16* __restrict__ W1F, float* __restrict__ accg) {
    int blk = blockIdx.x;
    if (blk >= 360) {
        int t = (blk - 360) * 256 + threadIdx.x;   // 8192 threads = 128 slots * 64 lanes
        int slot = t >> 6, l = t & 63;
        int nf = slot >> 3, ks = slot & 7;         // nf in [0,16): full N=256
        int n = nf * 16 + (l & 15);
        int kb = l >> 4;
        f16x8 wv;
        #pragma unroll
        for (int e = 0; e < 8; ++e) {
            int k = ks * 32 + kb * 8 + e;
            wv[e] = (_Float16)W1[k * DH + n];
        }
        reinterpret_cast<f16x8*>(W1F)[t] = wv;
        return;
    }
    int bb = blk / 45;
    int p0 = (blk % 45) * 5;
    if (blk % 45 == 0) accg[bb * DH + threadIdx.x] = 0.0f;   // replaces memset
    __shared__ float fl[5][DIN];
    int t = threadIdx.x;
    for (int idx = t; idx < 5 * DIN; idx += 256) {
        int pp = idx / DIN, f = idx % DIN;
        int p = p0 + pp;
        int r = p / PGRID, c = p % PGRID;
        float val;
        if (f < 128) {
            int ch = f >> 2, q = f & 3, ki = q >> 1, kj = q & 1;
            int R = r + ki, C = c + kj;                 // pooled coords (0..15)
            const float* xp = x + (((size_t)bb * 32 + ch) * 32 + 2 * R) * 32 + 2 * C;
            val = 0.25f * (xp[0] + xp[1] + xp[32] + xp[33]);
        } else {
            val = (f == 128) ? (float)(c - 7) : (float)(r - 7);  // cx, cy
        }
        fl[pp][f] = val;
    }
    __syncthreads();
    int n = t;  // 0..255
    float u[5] = {0, 0, 0, 0, 0}, v[5] = {0, 0, 0, 0, 0};
    for (int k = 0; k < DIN; ++k) {
        float wa = W0[k * DH + n];
        float wb = W0[(DIN + k) * DH + n];
        #pragma unroll
        for (int pp = 0; pp < 5; ++pp) {
            float f = fl[pp][k];
            u[pp] = fmaf(f, wa, u[pp]);
            v[pp] = fmaf(f, wb, v[pp]);
        }
    }
    float bb0 = b0[n];
    #pragma unroll
    for (int pp = 0; pp < 5; ++pp) {
        size_t base = ((size_t)bb * NP + p0 + pp) * DH + n;
        U[base] = (_Float16)(u[pp] + bb0);  // fold b0 into U
        V[base] = (_Float16)v[pp];
    }
}

// ---------------------------------------------------------------------------
// K2: main relational GEMM + reduce — WIDE-WAVE variant of R12.
// launch_bounds(256,1): 1 wave/SIMD, ~450-reg spill-free budget (m08/m24).
// Wave w = (mhalf=w>>1, nhalf=w&1): tile M=32 (2 mf-frags) x N=128 (8 nf).
//   bv[8][8] = 256 regs (pinned), acc[2][8] = 64, temps ~45 -> ~365 regs.
// Gains vs R12: A-reads halve (16 vs 32 b128/wave-iter -> block LDS 224->160)
// and NO MFMA-issue contention on the SIMD (was 2 waves sharing the pipe).
// Build mapping unchanged: wave w builds Af slots mf=w (consumers differ).
// V chunk DMA'd to LDS once per block; U staged once; 2-phase barrier loop.
__global__ __launch_bounds__(256, 1) void main_kernel(
        const _Float16* __restrict__ U, const _Float16* __restrict__ V,
        const _Float16* __restrict__ W1F, const float* __restrict__ b1,
        float* __restrict__ accg) {
    __shared__ f16x8 Af[2048];            // 32 KB: [mf(4)][ks(8)][lane(64)] x 16B
    __shared__ _Float16 Upad[16 * 264];   // 8.25 KB
    __shared__ _Float16 Vlds[28 * 256];   // 14 KB: chunk's V rows
    const int JT = 15, CHUNKS = 9, TILESPC = 7;  // 9*7=63 >= 57 i-tiles
    int blk = blockIdx.x;
    int bb = blk / (JT * CHUNKS);
    int rem = blk % (JT * CHUNKS);
    int jt = rem / CHUNKS, ch = rem % CHUNKS;
    int j0 = jt * 16;
    int tile0 = ch * TILESPC;
    int nt = min(TILESPC, 57 - tile0);
    int t = threadIdx.x, l = t & 63, w = t >> 6;
    int nhalf = w & 1, mhalf = w >> 1;

    // ---- DMA chunk V rows to LDS: 28 rows x 512B (tail reads ws garbage, masked)
    {
        const _Float16* Vsrc = V + ((size_t)bb * NP + tile0 * 4) * DH;
        for (int q = w * 4; q < 14 && q < w * 4 + 4; ++q) {
            __builtin_amdgcn_global_load_lds(
                (const __attribute__((address_space(1))) void*)(Vsrc + q * 512 + (size_t)l * 8),
                (__attribute__((address_space(3))) void*)(&Vlds[q * 512]),
                16, 0, 0);
        }
    }
    // ---- stage U tile once (f16, coalesced: 16 threads/row x 32B)
    {
        int jj = t >> 4, kk = (t & 15) * 16;   // kk in halfs
        int jc = j0 + jj; if (jc >= NP) jc = NP - 1;
        const f16x8* src = reinterpret_cast<const f16x8*>(U + ((size_t)bb * NP + jc) * DH + kk);
        *reinterpret_cast<f16x8*>(&Upad[jj * 264 + kk])     = src[0];
        *reinterpret_cast<f16x8*>(&Upad[jj * 264 + kk + 8]) = src[1];
    }
    // ---- B fragments: wave's N=128 slice = 64 frags = 256 regs, pinned in loop
    f16x8 bv[8][8];
    const f16x8* Bp = reinterpret_cast<const f16x8*>(W1F);
    #pragma unroll
    for (int nf = 0; nf < 8; ++nf)
        #pragma unroll
        for (int ks = 0; ks < 8; ++ks)
            bv[nf][ks] = Bp[((nhalf * 8 + nf) * 8 + ks) * 64 + l];
    float b1v[8];
    #pragma unroll
    for (int nf = 0; nf < 8; ++nf) b1v[nf] = b1[nhalf * 128 + nf * 16 + (l & 15)];
    int rowg = l >> 4;
    float jmask[4];
    #pragma unroll
    for (int r = 0; r < 4; ++r) jmask[r] = (j0 + rowg * 4 + r) < NP ? 1.0f : 0.0f;
    float psum[8] = {0.f, 0.f, 0.f, 0.f, 0.f, 0.f, 0.f, 0.f};
    int kb = l >> 4;
    const _Float16* Urow = &Upad[(l & 15) * 264 + kb * 8];
    __syncthreads();   // drains vmcnt (Vlds DMA) + makes Upad visible

    for (int itl = 0; itl < nt; ++itl) {
        // pin bv: keep all 64 frags resident (no rematerialization/reload)
        #pragma unroll
        for (int nf = 0; nf < 8; ++nf)
            #pragma unroll
            for (int ks = 0; ks < 8; ++ks)
                asm volatile("" : "+v"(bv[nf][ks]));

        int i0 = (tile0 + itl) * 4;
        const f16x8* Vrow = reinterpret_cast<const f16x8*>(&Vlds[(itl * 4 + w) * 256]);
        if (itl) __syncthreads();   // prev iter's A reads done before overwrite

        // ---- build A: wave w builds mf=w, 8 ks slots (packed-f16 math)
        #pragma unroll
        for (int ks = 0; ks < 8; ++ks) {
            f16x8 uv = *reinterpret_cast<const f16x8*>(Urow + ks * 32);
            f16x8 vv = Vrow[ks * 4 + kb];
            f16x8 s  = uv + vv;
            f16x8 a  = __builtin_elementwise_max(s, s * (_Float16)0.01f);
            Af[(w * 8 + ks) * 64 + l] = a;
        }
        __syncthreads();

        // ---- MFMA: wave computes mf in {2*mhalf, 2*mhalf+1}, nf 8-wide
        f32x4 acc[2][8];
        #pragma unroll
        for (int m2 = 0; m2 < 2; ++m2)
            #pragma unroll
            for (int nf = 0; nf < 8; ++nf)
                acc[m2][nf] = (f32x4){b1v[nf], b1v[nf], b1v[nf], b1v[nf]};
        #pragma unroll
        for (int ks = 0; ks < 8; ++ks) {
            f16x8 av[2];
            #pragma unroll
            for (int m2 = 0; m2 < 2; ++m2)
                av[m2] = Af[((mhalf * 2 + m2) * 8 + ks) * 64 + l];
            #pragma unroll
            for (int m2 = 0; m2 < 2; ++m2)
                #pragma unroll
                for (int nf = 0; nf < 8; ++nf)
                    acc[m2][nf] = __builtin_amdgcn_mfma_f32_16x16x32_f16(
                        av[m2], bv[nf][ks], acc[m2][nf], 0, 0, 0);
        }

        // ---- epilogue: lrelu + jmask-fma row-sum (wave-uniform mf skip)
        #pragma unroll
        for (int m2 = 0; m2 < 2; ++m2) {
            if (i0 + mhalf * 2 + m2 < NP) {
                #pragma unroll
                for (int r = 0; r < 4; ++r) {
                    #pragma unroll
                    for (int nf = 0; nf < 8; ++nf) {
                        float a = acc[m2][nf][r];
                        float h = fmaxf(a, 0.01f * a);
                        psum[nf] = fmaf(h, jmask[r], psum[nf]);
                    }
                }
            }
        }
    }

    // ---- block-level reduce + one atomicAdd set
    #pragma unroll
    for (int nf = 0; nf < 8; ++nf) {
        psum[nf] += __shfl_xor(psum[nf], 16);
        psum[nf] += __shfl_xor(psum[nf], 32);
    }
    if (l < 16) {
        #pragma unroll
        for (int nf = 0; nf < 8; ++nf)
            atomicAdd(&accg[bb * DH + nhalf * 128 + nf * 16 + l], psum[nf]);
    }
}

// ---------------------------------------------------------------------------
// K3: out[b,o] = (accg[b,:]/P^2) @ Wout + bout
__global__ void out_kernel(const float* __restrict__ accg, const float* __restrict__ Wout,
                           const float* __restrict__ bout, float* __restrict__ out) {
    int bb = blockIdx.x;
    int o = threadIdx.x;  // 0..127
    float s = 0.f;
    for (int n = 0; n < DH; ++n)
        s = fmaf(accg[bb * DH + n], Wout[n * 128 + o], s);
    out[bb * 128 + o] = s * (1.0f / 50625.0f) + bout[o];
}

// ---------------------------------------------------------------------------
extern "C" void kernel_launch(void* const* d_in, const int* in_sizes, int n_in,
                              void* d_out, int out_size, void* d_ws, size_t ws_size,
                              hipStream_t stream) {
    const float* x    = (const float*)d_in[0];
    const float* W0   = (const float*)d_in[1];
    const float* b0   = (const float*)d_in[2];
    const float* W1   = (const float*)d_in[3];
    const float* b1   = (const float*)d_in[4];
    const float* Wout = (const float*)d_in[5];
    const float* bout = (const float*)d_in[6];
    float* out = (float*)d_out;

    char* ws = (char*)d_ws;
    _Float16* U    = (_Float16*)(ws);                      // 8*225*256*2 =   921,600 B
    _Float16* V    = (_Float16*)(ws + 921600);             //                 921,600 B
    _Float16* W1F  = (_Float16*)(ws + 2 * 921600);         // 256*256*2  =   131,072 B
    float*    accg = (float*)(ws + 2 * 921600 + 131072);   // 8*256*4    =     8,192 B

    prep_kernel<<<392, 256, 0, stream>>>(x, W0, b0, W1, U, V, W1F, accg);
    main_kernel<<<NB * 15 * 9, 256, 0, stream>>>(U, V, W1F, b1, accg);
    out_kernel<<<NB, 128, 0, stream>>>(accg, Wout, bout, out);
}

// Round 14
// 102.029 us; speedup vs baseline: 1.2785x; 1.2785x over previous
//
#include <hip/hip_runtime.h>
#include <hip/hip_bf16.h>
#include <stdint.h>

// Problem constants
#define NB 8
#define NP 225      // patches per image
#define PGRID 15    // 15x15 patch grid
#define DH 256      // hidden
#define DIN 130     // per-node feature dim

typedef _Float16 f16x8 __attribute__((ext_vector_type(8)));   // 8 f16 = 4 VGPRs
typedef float    f32x4 __attribute__((ext_vector_type(4)));

static __device__ __forceinline__ float lrelu(float x) { return fmaxf(x, 0.01f * x); }

// ---------------------------------------------------------------------------
// K1 (fused prep): blocks 0..359 = pool+patch+U/V projection (f32 math, f16
// store) + accg zeroing; blocks 360..391 = W1 repack to fragment-linear f16.
__global__ void prep_kernel(const float* __restrict__ x, const float* __restrict__ W0,
                            const float* __restrict__ b0, const float* __restrict__ W1,
                            _Float16* __restrict__ U, _Float16* __restrict__ V,
                            _Float16* __restrict__ W1F, float* __restrict__ accg) {
    int blk = blockIdx.x;
    if (blk >= 360) {
        int t = (blk - 360) * 256 + threadIdx.x;   // 8192 threads = 128 slots * 64 lanes
        int slot = t >> 6, l = t & 63;
        int nf = slot >> 3, ks = slot & 7;
        int n = nf * 16 + (l & 15);
        int kb = l >> 4;
        f16x8 wv;
        #pragma unroll
        for (int e = 0; e < 8; ++e) {
            int k = ks * 32 + kb * 8 + e;
            wv[e] = (_Float16)W1[k * DH + n];
        }
        reinterpret_cast<f16x8*>(W1F)[t] = wv;
        return;
    }
    int bb = blk / 45;
    int p0 = (blk % 45) * 5;
    if (blk % 45 == 0) accg[bb * DH + threadIdx.x] = 0.0f;   // replaces memset
    __shared__ float fl[5][DIN];
    int t = threadIdx.x;
    for (int idx = t; idx < 5 * DIN; idx += 256) {
        int pp = idx / DIN, f = idx % DIN;
        int p = p0 + pp;
        int r = p / PGRID, c = p % PGRID;
        float val;
        if (f < 128) {
            int ch = f >> 2, q = f & 3, ki = q >> 1, kj = q & 1;
            int R = r + ki, C = c + kj;                 // pooled coords (0..15)
            const float* xp = x + (((size_t)bb * 32 + ch) * 32 + 2 * R) * 32 + 2 * C;
            val = 0.25f * (xp[0] + xp[1] + xp[32] + xp[33]);
        } else {
            val = (f == 128) ? (float)(c - 7) : (float)(r - 7);  // cx, cy
        }
        fl[pp][f] = val;
    }
    __syncthreads();
    int n = t;  // 0..255
    float u[5] = {0, 0, 0, 0, 0}, v[5] = {0, 0, 0, 0, 0};
    for (int k = 0; k < DIN; ++k) {
        float wa = W0[k * DH + n];
        float wb = W0[(DIN + k) * DH + n];
        #pragma unroll
        for (int pp = 0; pp < 5; ++pp) {
            float f = fl[pp][k];
            u[pp] = fmaf(f, wa, u[pp]);
            v[pp] = fmaf(f, wb, v[pp]);
        }
    }
    float bb0 = b0[n];
    #pragma unroll
    for (int pp = 0; pp < 5; ++pp) {
        size_t base = ((size_t)bb * NP + p0 + pp) * DH + n;
        U[base] = (_Float16)(u[pp] + bb0);  // fold b0 into U
        V[base] = (_Float16)v[pp];
    }
}

// ---------------------------------------------------------------------------
// K2: main relational GEMM + reduce — REGISTER-A, barrier-free loop.
// R12 spent ~half its LDS budget on the Af round-trip (A-writes 32 + A-reads
// 128 b128/block-iter) purely to share A across waves, and its 2 barriers/iter
// phase-locked the waves. Here each wave rebuilds all 4 mf A-frags itself
// (12 pk-f16 instrs/frag — cheap) from U(LDS) + V(LDS, DMA'd per chunk) and
// feeds MFMA directly from registers. LDS/block-iter: 224 -> 160 b128, all
// reads; NO barriers in the loop -> the 2 waves/SIMD drift and overlap
// MFMA/VALU/LDS pipes (m114). R8's failure mode is absent: V latency is LDS
// (~120cyc, ILP-hidden), not global, and no union scratch.
// bv[4][8]=128 regs lives in the unified AGPR side (R12 evidence: resident at
// VGPR_Count=128, no spill); acc in AGPRs.
__global__ __launch_bounds__(256, 2) void main_kernel(
        const _Float16* __restrict__ U, const _Float16* __restrict__ V,
        const _Float16* __restrict__ W1F, const float* __restrict__ b1,
        float* __restrict__ accg) {
    __shared__ _Float16 Upad[16 * 264];   // 8.25 KB
    __shared__ _Float16 Vlds[28 * 256];   // 14 KB: chunk's V rows
    const int JT = 15, CHUNKS = 9, TILESPC = 7;  // 9*7=63 >= 57 i-tiles
    int blk = blockIdx.x;
    int bb = blk / (JT * CHUNKS);
    int rem = blk % (JT * CHUNKS);
    int jt = rem / CHUNKS, ch = rem % CHUNKS;
    int j0 = jt * 16;
    int tile0 = ch * TILESPC;
    int nt = min(TILESPC, 57 - tile0);
    int t = threadIdx.x, l = t & 63, w = t >> 6;

    // ---- DMA chunk V rows to LDS: 28 rows x 512B (tail reads ws garbage;
    // masked in epilogue by the wave-uniform i<NP skip)
    {
        const _Float16* Vsrc = V + ((size_t)bb * NP + tile0 * 4) * DH;
        for (int q = w * 4; q < 14 && q < w * 4 + 4; ++q) {
            __builtin_amdgcn_global_load_lds(
                (const __attribute__((address_space(1))) void*)(Vsrc + q * 512 + (size_t)l * 8),
                (__attribute__((address_space(3))) void*)(&Vlds[q * 512]),
                16, 0, 0);
        }
    }
    // ---- stage U tile once (f16, coalesced: 16 threads/row x 32B)
    {
        int jj = t >> 4, kk = (t & 15) * 16;   // kk in halfs
        int jc = j0 + jj; if (jc >= NP) jc = NP - 1;
        const f16x8* src = reinterpret_cast<const f16x8*>(U + ((size_t)bb * NP + jc) * DH + kk);
        *reinterpret_cast<f16x8*>(&Upad[jj * 264 + kk])     = src[0];
        *reinterpret_cast<f16x8*>(&Upad[jj * 264 + kk + 8]) = src[1];
    }
    // ---- B fragments (wave's N=64 slice): 32 frags = 128 regs
    f16x8 bv[4][8];
    const f16x8* Bp = reinterpret_cast<const f16x8*>(W1F);
    #pragma unroll
    for (int nf = 0; nf < 4; ++nf)
        #pragma unroll
        for (int ks = 0; ks < 8; ++ks)
            bv[nf][ks] = Bp[((w * 4 + nf) * 8 + ks) * 64 + l];
    float b1v[4];
    #pragma unroll
    for (int nf = 0; nf < 4; ++nf) b1v[nf] = b1[w * 64 + nf * 16 + (l & 15)];
    int rowg = l >> 4;
    float jmask[4];
    #pragma unroll
    for (int r = 0; r < 4; ++r) jmask[r] = (j0 + rowg * 4 + r) < NP ? 1.0f : 0.0f;
    float psum[4] = {0.f, 0.f, 0.f, 0.f};
    int kb = l >> 4;
    const _Float16* Urow = &Upad[(l & 15) * 264 + kb * 8];
    __syncthreads();   // drains vmcnt (Vlds DMA) + makes Upad visible; ONLY barrier

    for (int itl = 0; itl < nt; ++itl) {
        // pin bv resident across the iteration (no remat/reload)
        #pragma unroll
        for (int nf = 0; nf < 4; ++nf)
            #pragma unroll
            for (int ks = 0; ks < 8; ++ks)
                asm volatile("" : "+v"(bv[nf][ks]));

        int i0 = (tile0 + itl) * 4;
        f32x4 acc[4][4];
        #pragma unroll
        for (int mf = 0; mf < 4; ++mf)
            #pragma unroll
            for (int nf = 0; nf < 4; ++nf)
                acc[mf][nf] = (f32x4){b1v[nf], b1v[nf], b1v[nf], b1v[nf]};

        #pragma unroll
        for (int ks = 0; ks < 8; ++ks) {
            f16x8 uv = *reinterpret_cast<const f16x8*>(Urow + ks * 32);
            #pragma unroll
            for (int mf = 0; mf < 4; ++mf) {
                // V row for this mf (broadcast read: 16 lanes share an address)
                f16x8 vv = *reinterpret_cast<const f16x8*>(
                    &Vlds[(itl * 4 + mf) * 256 + kb * 8 + ks * 32]);
                f16x8 s = uv + vv;
                f16x8 a = __builtin_elementwise_max(s, s * (_Float16)0.01f);
                #pragma unroll
                for (int nf = 0; nf < 4; ++nf)
                    acc[mf][nf] = __builtin_amdgcn_mfma_f32_16x16x32_f16(
                        a, bv[nf][ks], acc[mf][nf], 0, 0, 0);
            }
        }

        // ---- epilogue: lrelu + jmask-fma row-sum (wave-uniform mf skip)
        #pragma unroll
        for (int mf = 0; mf < 4; ++mf) {
            if (i0 + mf < NP) {
                #pragma unroll
                for (int r = 0; r < 4; ++r) {
                    #pragma unroll
                    for (int nf = 0; nf < 4; ++nf) {
                        float a = acc[mf][nf][r];
                        float h = fmaxf(a, 0.01f * a);
                        psum[nf] = fmaf(h, jmask[r], psum[nf]);
                    }
                }
            }
        }
    }

    // ---- block-level reduce + one atomicAdd set
    #pragma unroll
    for (int nf = 0; nf < 4; ++nf) {
        psum[nf] += __shfl_xor(psum[nf], 16);
        psum[nf] += __shfl_xor(psum[nf], 32);
    }
    if (l < 16) {
        #pragma unroll
        for (int nf = 0; nf < 4; ++nf)
            atomicAdd(&accg[bb * DH + w * 64 + nf * 16 + l], psum[nf]);
    }
}

// ---------------------------------------------------------------------------
// K3: out[b,o] = (accg[b,:]/P^2) @ Wout + bout
__global__ void out_kernel(const float* __restrict__ accg, const float* __restrict__ Wout,
                           const float* __restrict__ bout, float* __restrict__ out) {
    int bb = blockIdx.x;
    int o = threadIdx.x;  // 0..127
    float s = 0.f;
    for (int n = 0; n < DH; ++n)
        s = fmaf(accg[bb * DH + n], Wout[n * 128 + o], s);
    out[bb * 128 + o] = s * (1.0f / 50625.0f) + bout[o];
}

// ---------------------------------------------------------------------------
extern "C" void kernel_launch(void* const* d_in, const int* in_sizes, int n_in,
                              void* d_out, int out_size, void* d_ws, size_t ws_size,
                              hipStream_t stream) {
    const float* x    = (const float*)d_in[0];
    const float* W0   = (const float*)d_in[1];
    const float* b0   = (const float*)d_in[2];
    const float* W1   = (const float*)d_in[3];
    const float* b1   = (const float*)d_in[4];
    const float* Wout = (const float*)d_in[5];
    const float* bout = (const float*)d_in[6];
    float* out = (float*)d_out;

    char* ws = (char*)d_ws;
    _Float16* U    = (_Float16*)(ws);                      // 8*225*256*2 =   921,600 B
    _Float16* V    = (_Float16*)(ws + 921600);             //                 921,600 B
    _Float16* W1F  = (_Float16*)(ws + 2 * 921600);         // 256*256*2  =   131,072 B
    float*    accg = (float*)(ws + 2 * 921600 + 131072);   // 8*256*4    =     8,192 B

    prep_kernel<<<392, 256, 0, stream>>>(x, W0, b0, W1, U, V, W1F, accg);
    main_kernel<<<NB * 15 * 9, 256, 0, stream>>>(U, V, W1F, b1, accg);
    out_kernel<<<NB, 128, 0, stream>>>(accg, Wout, bout, out);
}

// Round 15
// 97.379 us; speedup vs baseline: 1.3396x; 1.0477x over previous
//
#include <hip/hip_runtime.h>
#include <hip/hip_bf16.h>
#include <stdint.h>

// Problem constants
#define NB 8
#define NP 225      // patches per image
#define PGRID 15    // 15x15 patch grid
#define DH 256      // hidden
#define DIN 130     // per-node feature dim

typedef _Float16 f16x8 __attribute__((ext_vector_type(8)));   // 8 f16 = 4 VGPRs
typedef float    f32x4 __attribute__((ext_vector_type(4)));

static __device__ __forceinline__ float lrelu(float x) { return fmaxf(x, 0.01f * x); }

// ---------------------------------------------------------------------------
// K1 (fused prep): blocks 0..359 = pool+patch+U/V projection (f32 math, f16
// store) + accg zeroing; blocks 360..391 = W1 repack to fragment-linear f16.
__global__ void prep_kernel(const float* __restrict__ x, const float* __restrict__ W0,
                            const float* __restrict__ b0, const float* __restrict__ W1,
                            _Float16* __restrict__ U, _Float16* __restrict__ V,
                            _Float16* __restrict__ W1F, float* __restrict__ accg) {
    int blk = blockIdx.x;
    if (blk >= 360) {
        int t = (blk - 360) * 256 + threadIdx.x;   // 8192 threads = 128 slots * 64 lanes
        int slot = t >> 6, l = t & 63;
        int nf = slot >> 3, ks = slot & 7;
        int n = nf * 16 + (l & 15);
        int kb = l >> 4;
        f16x8 wv;
        #pragma unroll
        for (int e = 0; e < 8; ++e) {
            int k = ks * 32 + kb * 8 + e;
            wv[e] = (_Float16)W1[k * DH + n];
        }
        reinterpret_cast<f16x8*>(W1F)[t] = wv;
        return;
    }
    int bb = blk / 45;
    int p0 = (blk % 45) * 5;
    if (blk % 45 == 0) accg[bb * DH + threadIdx.x] = 0.0f;   // replaces memset
    __shared__ float fl[5][DIN];
    int t = threadIdx.x;
    for (int idx = t; idx < 5 * DIN; idx += 256) {
        int pp = idx / DIN, f = idx % DIN;
        int p = p0 + pp;
        int r = p / PGRID, c = p % PGRID;
        float val;
        if (f < 128) {
            int ch = f >> 2, q = f & 3, ki = q >> 1, kj = q & 1;
            int R = r + ki, C = c + kj;                 // pooled coords (0..15)
            const float* xp = x + (((size_t)bb * 32 + ch) * 32 + 2 * R) * 32 + 2 * C;
            val = 0.25f * (xp[0] + xp[1] + xp[32] + xp[33]);
        } else {
            val = (f == 128) ? (float)(c - 7) : (float)(r - 7);  // cx, cy
        }
        fl[pp][f] = val;
    }
    __syncthreads();
    int n = t;  // 0..255
    float u[5] = {0, 0, 0, 0, 0}, v[5] = {0, 0, 0, 0, 0};
    for (int k = 0; k < DIN; ++k) {
        float wa = W0[k * DH + n];
        float wb = W0[(DIN + k) * DH + n];
        #pragma unroll
        for (int pp = 0; pp < 5; ++pp) {
            float f = fl[pp][k];
            u[pp] = fmaf(f, wa, u[pp]);
            v[pp] = fmaf(f, wb, v[pp]);
        }
    }
    float bb0 = b0[n];
    #pragma unroll
    for (int pp = 0; pp < 5; ++pp) {
        size_t base = ((size_t)bb * NP + p0 + pp) * DH + n;
        U[base] = (_Float16)(u[pp] + bb0);  // fold b0 into U
        V[base] = (_Float16)v[pp];
    }
}

// ---------------------------------------------------------------------------
// K2: main relational GEMM + reduce — R12 + minimal T3 2-phase pipeline.
// R12's PMC: matrix 2483 + LDS 2690 cyc/block-iter run SERIALLY (5340 total)
// because barriers bunch all waves into {build: LDS burst}/{MFMA: matrix
// burst} phases. Fix: split K into halves; Af double-buffered (2 x 16KB);
// each barrier segment = build(next half -> other buf) || MFMA(current half)
// — independent, same segment, so LDS/VALU interleaves with matrix ops.
// Same 2 barriers/itl as R12. kh is compile-time in each segment (macros) so
// bv indexing stays static (rule #20). LDS 54KB -> 2 blocks/CU.
// Wave w: builds A slots mf=w; consumes full A with its N=64 slice bv (128
// regs, resident per R12 evidence). V chunk DMA'd to LDS; U staged once.
__global__ __launch_bounds__(256, 2) void main_kernel(
        const _Float16* __restrict__ U, const _Float16* __restrict__ V,
        const _Float16* __restrict__ W1F, const float* __restrict__ b1,
        float* __restrict__ accg) {
    __shared__ f16x8 Af[2][1024];         // 2 x 16 KB: [mf(4)][ksh(4)][lane(64)]
    __shared__ _Float16 Upad[16 * 264];   // 8.25 KB
    __shared__ _Float16 Vlds[28 * 256];   // 14 KB: chunk's V rows
    const int JT = 15, CHUNKS = 9, TILESPC = 7;  // 9*7=63 >= 57 i-tiles
    int blk = blockIdx.x;
    int bb = blk / (JT * CHUNKS);
    int rem = blk % (JT * CHUNKS);
    int jt = rem / CHUNKS, ch = rem % CHUNKS;
    int j0 = jt * 16;
    int tile0 = ch * TILESPC;
    int nt = min(TILESPC, 57 - tile0);
    int t = threadIdx.x, l = t & 63, w = t >> 6;

    // ---- DMA chunk V rows to LDS: 28 rows x 512B (tail reads ws garbage;
    // masked in epilogue by the wave-uniform i<NP skip)
    {
        const _Float16* Vsrc = V + ((size_t)bb * NP + tile0 * 4) * DH;
        for (int q = w * 4; q < 14 && q < w * 4 + 4; ++q) {
            __builtin_amdgcn_global_load_lds(
                (const __attribute__((address_space(1))) void*)(Vsrc + q * 512 + (size_t)l * 8),
                (__attribute__((address_space(3))) void*)(&Vlds[q * 512]),
                16, 0, 0);
        }
    }
    // ---- stage U tile once (f16, coalesced: 16 threads/row x 32B)
    {
        int jj = t >> 4, kk = (t & 15) * 16;   // kk in halfs
        int jc = j0 + jj; if (jc >= NP) jc = NP - 1;
        const f16x8* src = reinterpret_cast<const f16x8*>(U + ((size_t)bb * NP + jc) * DH + kk);
        *reinterpret_cast<f16x8*>(&Upad[jj * 264 + kk])     = src[0];
        *reinterpret_cast<f16x8*>(&Upad[jj * 264 + kk + 8]) = src[1];
    }
    // ---- B fragments (wave's N=64 slice): 32 frags = 128 regs
    f16x8 bv[4][8];
    const f16x8* Bp = reinterpret_cast<const f16x8*>(W1F);
    #pragma unroll
    for (int nf = 0; nf < 4; ++nf)
        #pragma unroll
        for (int ks = 0; ks < 8; ++ks)
            bv[nf][ks] = Bp[((w * 4 + nf) * 8 + ks) * 64 + l];
    float b1v[4];
    #pragma unroll
    for (int nf = 0; nf < 4; ++nf) b1v[nf] = b1[w * 64 + nf * 16 + (l & 15)];
    int rowg = l >> 4;
    float jmask[4];
    #pragma unroll
    for (int r = 0; r < 4; ++r) jmask[r] = (j0 + rowg * 4 + r) < NP ? 1.0f : 0.0f;
    float psum[4] = {0.f, 0.f, 0.f, 0.f};
    int kb = l >> 4;
    const _Float16* Urow = &Upad[(l & 15) * 264 + kb * 8];

// build half KH of i-tile ITL2 into buffer BUF (wave w builds mf=w slots)
#define BUILD_HALF(ITL2, KH, BUF)                                            \
    {                                                                        \
        const _Float16* Vr = &Vlds[((ITL2) * 4 + w) * 256 + kb * 8];         \
        _Pragma("unroll")                                                    \
        for (int q = 0; q < 4; ++q) {                                        \
            int ks_ = (KH) * 4 + q;                                          \
            f16x8 uv = *reinterpret_cast<const f16x8*>(Urow + ks_ * 32);     \
            f16x8 vv = *reinterpret_cast<const f16x8*>(Vr + ks_ * 32);       \
            f16x8 s_ = uv + vv;                                              \
            f16x8 a_ = __builtin_elementwise_max(s_, s_ * (_Float16)0.01f);  \
            Af[BUF][(w * 4 + q) * 64 + l] = a_;                              \
        }                                                                    \
    }

// MFMA on buffer BUF holding half KH (bv index compile-time)
#define MFMA_HALF(KH, BUF)                                                   \
    _Pragma("unroll")                                                        \
    for (int ksh = 0; ksh < 4; ++ksh) {                                      \
        f16x8 av[4];                                                         \
        _Pragma("unroll")                                                    \
        for (int mf = 0; mf < 4; ++mf) av[mf] = Af[BUF][(mf * 4 + ksh) * 64 + l]; \
        _Pragma("unroll")                                                    \
        for (int mf = 0; mf < 4; ++mf)                                       \
            _Pragma("unroll")                                                \
            for (int nf = 0; nf < 4; ++nf)                                   \
                acc[mf][nf] = __builtin_amdgcn_mfma_f32_16x16x32_f16(        \
                    av[mf], bv[nf][(KH) * 4 + ksh], acc[mf][nf], 0, 0, 0);   \
    }

    __syncthreads();          // Vlds DMA drained + Upad visible
    BUILD_HALF(0, 0, 0);      // prologue: first half of first tile
    __syncthreads();
    int cur = 0;

    for (int itl = 0; itl < nt; ++itl) {
        int i0 = (tile0 + itl) * 4;
        f32x4 acc[4][4];
        #pragma unroll
        for (int mf = 0; mf < 4; ++mf)
            #pragma unroll
            for (int nf = 0; nf < 4; ++nf)
                acc[mf][nf] = (f32x4){b1v[nf], b1v[nf], b1v[nf], b1v[nf]};

        // segment A: build(itl, half1 -> other buf) || MFMA(half0 from cur)
        BUILD_HALF(itl, 1, cur ^ 1);
        MFMA_HALF(0, cur);
        __syncthreads();
        cur ^= 1;

        // segment B: build(itl+1, half0 -> other buf) || MFMA(half1 from cur)
        if (itl + 1 < nt) BUILD_HALF(itl + 1, 0, cur ^ 1);
        MFMA_HALF(1, cur);

        // epilogue: lrelu + jmask-fma row-sum (wave-uniform mf skip)
        #pragma unroll
        for (int mf = 0; mf < 4; ++mf) {
            if (i0 + mf < NP) {
                #pragma unroll
                for (int r = 0; r < 4; ++r) {
                    #pragma unroll
                    for (int nf = 0; nf < 4; ++nf) {
                        float a = acc[mf][nf][r];
                        float h = fmaxf(a, 0.01f * a);
                        psum[nf] = fmaf(h, jmask[r], psum[nf]);
                    }
                }
            }
        }
        __syncthreads();
        cur ^= 1;
    }

    // ---- block-level reduce + one atomicAdd set
    #pragma unroll
    for (int nf = 0; nf < 4; ++nf) {
        psum[nf] += __shfl_xor(psum[nf], 16);
        psum[nf] += __shfl_xor(psum[nf], 32);
    }
    if (l < 16) {
        #pragma unroll
        for (int nf = 0; nf < 4; ++nf)
            atomicAdd(&accg[bb * DH + w * 64 + nf * 16 + l], psum[nf]);
    }
#undef BUILD_HALF
#undef MFMA_HALF
}

// ---------------------------------------------------------------------------
// K3: out[b,o] = (accg[b,:]/P^2) @ Wout + bout
__global__ void out_kernel(const float* __restrict__ accg, const float* __restrict__ Wout,
                           const float* __restrict__ bout, float* __restrict__ out) {
    int bb = blockIdx.x;
    int o = threadIdx.x;  // 0..127
    float s = 0.f;
    for (int n = 0; n < DH; ++n)
        s = fmaf(accg[bb * DH + n], Wout[n * 128 + o], s);
    out[bb * 128 + o] = s * (1.0f / 50625.0f) + bout[o];
}

// ---------------------------------------------------------------------------
extern "C" void kernel_launch(void* const* d_in, const int* in_sizes, int n_in,
                              void* d_out, int out_size, void* d_ws, size_t ws_size,
                              hipStream_t stream) {
    const float* x    = (const float*)d_in[0];
    const float* W0   = (const float*)d_in[1];
    const float* b0   = (const float*)d_in[2];
    const float* W1   = (const float*)d_in[3];
    const float* b1   = (const float*)d_in[4];
    const float* Wout = (const float*)d_in[5];
    const float* bout = (const float*)d_in[6];
    float* out = (float*)d_out;

    char* ws = (char*)d_ws;
    _Float16* U    = (_Float16*)(ws);                      // 8*225*256*2 =   921,600 B
    _Float16* V    = (_Float16*)(ws + 921600);             //                 921,600 B
    _Float16* W1F  = (_Float16*)(ws + 2 * 921600);         // 256*256*2  =   131,072 B
    float*    accg = (float*)(ws + 2 * 921600 + 131072);   // 8*256*4    =     8,192 B

    prep_kernel<<<392, 256, 0, stream>>>(x, W0, b0, W1, U, V, W1F, accg);
    main_kernel<<<NB * 15 * 9, 256, 0, stream>>>(U, V, W1F, b1, accg);
    out_kernel<<<NB, 128, 0, stream>>>(accg, Wout, bout, out);
}